// Round 1
// baseline (170.231 us; speedup 1.0000x reference)
//
#include <hip/hip_runtime.h>

#define CCH 128      // channels
#define WIN 128      // time window (only last 128 steps matter; exact, see analysis)
#define TLEN 2048
#define NBATCH 8
#define NATOMS 3584
#define NEG 0.2f

__device__ __forceinline__ float lrelu(float v) { return v >= 0.f ? v : NEG * v; }

// ---------------------------------------------------------------------------
// Kernel A: h0[b][w][c] for the last WIN positions.
// grid (16, 8) blocks, 128 threads. Each block: 8 positions of one batch.
// ---------------------------------------------------------------------------
__global__ void k_setup(const float* __restrict__ x,
                        const float* __restrict__ embed_w,
                        const float* __restrict__ posamp_w,
                        const float* __restrict__ posamp_b,
                        const float* __restrict__ reduce_w,
                        const float* __restrict__ reduce_b,
                        float* __restrict__ h0)
{
    const int b  = blockIdx.y;
    const int w0 = blockIdx.x * 8;
    const int c  = threadIdx.x;

    __shared__ float cat[8][2 * CCH];

    const float pw0 = posamp_w[2 * c];
    const float pw1 = posamp_w[2 * c + 1];
    const float pb  = posamp_b[c];
    const float* xb = x + b * 4 * TLEN;

    for (int p = 0; p < 8; ++p) {
        int t = TLEN - WIN + w0 + p;
        int idx = (int)xb[t];              // channel 0: atom id (exact int in f32)
        float pos = xb[TLEN + t];          // channel 1
        float amp = xb[2 * TLEN + t];      // channel 2
        cat[p][c]        = embed_w[idx * CCH + c];
        cat[p][CCH + c]  = pw0 * pos + pw1 * amp + pb;
    }
    __syncthreads();

    const float* rw = reduce_w + c * (2 * CCH);
    float acc[8];
    const float rb = reduce_b[c];
    #pragma unroll
    for (int p = 0; p < 8; ++p) acc[p] = rb;

    for (int j = 0; j < 2 * CCH; ++j) {
        float wv = rw[j];
        #pragma unroll
        for (int p = 0; p < 8; ++p) acc[p] += wv * cat[p][j];
    }
    for (int p = 0; p < 8; ++p)
        h0[(b * WIN + w0 + p) * CCH + c] = acc[p];
}

// ---------------------------------------------------------------------------
// Kernel B: one residual dilated block.
//   y = dilconv3(h) + dil_b ; z = one_w @ y + one_b ; h' = lrelu(z + h)
// grid (16, 8) blocks, 256 threads. Block: 8 positions of one batch.
// Out-of-window columns are zero (exact for right edge; left-edge error never
// reaches w=127 — contamination max is w<=121 after all 6 layers).
// ---------------------------------------------------------------------------
__global__ void k_layer(const float* __restrict__ hin,
                        const float* __restrict__ dil_w,   // [C][C][3] (layer slice)
                        const float* __restrict__ dil_b,   // [C]
                        const float* __restrict__ one_w,   // [C][C]
                        const float* __restrict__ one_b,   // [C]
                        float* __restrict__ hout,
                        int d)
{
    const int b   = blockIdx.y;
    const int w0  = blockIdx.x * 8;
    const int tid = threadIdx.x;
    const int o   = tid & (CCH - 1);
    const int hi  = tid >> 7;          // 0..1

    __shared__ float cols[3][8][CCH];  // taps -d, 0, +d
    __shared__ float ybuf[8][CCH];

    // stage 24 columns (float4, coalesced); 768 float4 loads over 256 threads
    const float* hb = hin + b * WIN * CCH;
    for (int v = tid; v < 768; v += 256) {
        int tap = v >> 8;          // 0..2
        int rem = v & 255;
        int col = rem >> 5;        // 0..7
        int f4  = rem & 31;        // 0..31
        int wp  = w0 + col + (tap - 1) * d;
        float4 val = make_float4(0.f, 0.f, 0.f, 0.f);
        if (wp >= 0 && wp < WIN)
            val = *(const float4*)(hb + wp * CCH + f4 * 4);
        *(float4*)(&cols[tap][col][f4 * 4]) = val;
    }
    __syncthreads();

    // dilated conv: thread owns channel o, 4 time slots (hi*4 + r)
    const float* Wr = dil_w + o * CCH * 3;
    const float* lm = &cols[0][hi * 4][0];
    const float* lc = &cols[1][hi * 4][0];
    const float* lp = &cols[2][hi * 4][0];
    float a0 = 0.f, a1 = 0.f, a2 = 0.f, a3 = 0.f;
    #pragma unroll 4
    for (int i = 0; i < CCH; ++i) {
        float w0v = Wr[3 * i], w1v = Wr[3 * i + 1], w2v = Wr[3 * i + 2];
        a0 += w0v * lm[0 * CCH + i] + w1v * lc[0 * CCH + i] + w2v * lp[0 * CCH + i];
        a1 += w0v * lm[1 * CCH + i] + w1v * lc[1 * CCH + i] + w2v * lp[1 * CCH + i];
        a2 += w0v * lm[2 * CCH + i] + w1v * lc[2 * CCH + i] + w2v * lp[2 * CCH + i];
        a3 += w0v * lm[3 * CCH + i] + w1v * lc[3 * CCH + i] + w2v * lp[3 * CCH + i];
    }
    const float db = dil_b[o];
    ybuf[hi * 4 + 0][o] = a0 + db;
    ybuf[hi * 4 + 1][o] = a1 + db;
    ybuf[hi * 4 + 2][o] = a2 + db;
    ybuf[hi * 4 + 3][o] = a3 + db;
    __syncthreads();

    // 1x1 conv + residual + lrelu
    const float* Or = one_w + o * CCH;
    const float* y0 = &ybuf[hi * 4][0];
    float z0 = 0.f, z1 = 0.f, z2 = 0.f, z3 = 0.f;
    #pragma unroll 4
    for (int c2 = 0; c2 < CCH; ++c2) {
        float wv = Or[c2];
        z0 += wv * y0[0 * CCH + c2];
        z1 += wv * y0[1 * CCH + c2];
        z2 += wv * y0[2 * CCH + c2];
        z3 += wv * y0[3 * CCH + c2];
    }
    const float ob = one_b[o];
    float* outp = hout + (b * WIN + w0) * CCH;
    outp[(hi * 4 + 0) * CCH + o] = lrelu(z0 + ob + lc[0 * CCH + o]);
    outp[(hi * 4 + 1) * CCH + o] = lrelu(z1 + ob + lc[1 * CCH + o]);
    outp[(hi * 4 + 2) * CCH + o] = lrelu(z2 + ob + lc[2 * CCH + o]);
    outp[(hi * 4 + 3) * CCH + o] = lrelu(z3 + ob + lc[3 * CCH + o]);
}

// ---------------------------------------------------------------------------
// Kernel C: output stacks on the last column only.
// grid (29, 8), 128 threads. Blocks 0..27: atom logits rows j*128..; block 28: pa.
// ---------------------------------------------------------------------------
__global__ void k_final(const float* __restrict__ hfin,
                        const float* __restrict__ aw1, const float* __restrict__ ab1,
                        const float* __restrict__ aw2, const float* __restrict__ ab2,
                        const float* __restrict__ aw3, const float* __restrict__ ab3,
                        const float* __restrict__ pw1, const float* __restrict__ pb1,
                        const float* __restrict__ pw2, const float* __restrict__ pb2,
                        const float* __restrict__ pw3, const float* __restrict__ pb3,
                        float* __restrict__ out)
{
    const int b = blockIdx.y;
    const int j = blockIdx.x;
    const int c = threadIdx.x;

    __shared__ float hf[CCH], h1[CCH], h2[CCH];
    hf[c] = hfin[(b * WIN + (WIN - 1)) * CCH + c];
    __syncthreads();

    const bool is_pa = (j == 28);
    const float* w1 = is_pa ? pw1 : aw1;  const float* b1 = is_pa ? pb1 : ab1;
    const float* w2 = is_pa ? pw2 : aw2;  const float* b2 = is_pa ? pb2 : ab2;

    float s = b1[c];
    const float* r1 = w1 + c * CCH;
    for (int k = 0; k < CCH; ++k) s += r1[k] * hf[k];
    h1[c] = lrelu(s);
    __syncthreads();

    s = b2[c];
    const float* r2 = w2 + c * CCH;
    for (int k = 0; k < CCH; ++k) s += r2[k] * h1[k];
    h2[c] = lrelu(s);
    __syncthreads();

    if (!is_pa) {
        int ro = j * CCH + c;
        float s3 = ab3[ro];
        const float* r3 = aw3 + ro * CCH;
        for (int k = 0; k < CCH; ++k) s3 += r3[k] * h2[k];
        out[b * NATOMS + ro] = s3;
    } else if (c < 2) {
        float s3 = pb3[c];
        const float* r3 = pw3 + c * CCH;
        for (int k = 0; k < CCH; ++k) s3 += r3[k] * h2[k];
        out[NBATCH * NATOMS + b * 2 + c] = s3;
    }
}

// ---------------------------------------------------------------------------
extern "C" void kernel_launch(void* const* d_in, const int* in_sizes, int n_in,
                              void* d_out, int out_size, void* d_ws, size_t ws_size,
                              hipStream_t stream)
{
    const float* x        = (const float*)d_in[0];
    const float* embed_w  = (const float*)d_in[1];
    const float* posamp_w = (const float*)d_in[2];
    const float* posamp_b = (const float*)d_in[3];
    const float* reduce_w = (const float*)d_in[4];
    const float* reduce_b = (const float*)d_in[5];
    const float* dil_w    = (const float*)d_in[6];
    const float* dil_b    = (const float*)d_in[7];
    const float* one_w    = (const float*)d_in[8];
    const float* one_b    = (const float*)d_in[9];
    const float* aw1 = (const float*)d_in[10]; const float* ab1 = (const float*)d_in[11];
    const float* aw2 = (const float*)d_in[12]; const float* ab2 = (const float*)d_in[13];
    const float* aw3 = (const float*)d_in[14]; const float* ab3 = (const float*)d_in[15];
    const float* pw1 = (const float*)d_in[16]; const float* pb1 = (const float*)d_in[17];
    const float* pw2 = (const float*)d_in[18]; const float* pb2 = (const float*)d_in[19];
    const float* pw3 = (const float*)d_in[20]; const float* pb3 = (const float*)d_in[21];

    float* buf0 = (float*)d_ws;                       // [8][128][128] f32
    float* buf1 = buf0 + NBATCH * WIN * CCH;          // ping-pong

    k_setup<<<dim3(16, NBATCH), 128, 0, stream>>>(
        x, embed_w, posamp_w, posamp_b, reduce_w, reduce_b, buf0);

    const int dil[6] = {1, 3, 9, 27, 81, 1};
    float* bufs[2] = {buf0, buf1};
    int cur = 0;
    for (int l = 0; l < 6; ++l) {
        k_layer<<<dim3(16, NBATCH), 256, 0, stream>>>(
            bufs[cur],
            dil_w + (size_t)l * CCH * CCH * 3,
            dil_b + (size_t)l * CCH,
            one_w + (size_t)l * CCH * CCH,
            one_b + (size_t)l * CCH,
            bufs[cur ^ 1], dil[l]);
        cur ^= 1;
    }

    k_final<<<dim3(29, NBATCH), 128, 0, stream>>>(
        bufs[cur], aw1, ab1, aw2, ab2, aw3, ab3,
        pw1, pb1, pw2, pb2, pw3, pb3, (float*)d_out);
}